// Round 2
// 466.401 us; speedup vs baseline: 1.0531x; 1.0531x over previous
//
#include <hip/hip_runtime.h>

#define N_NODES 50000
#define N_EDGES 800000
#define IN_DIM 512
#define NEG_SLOPE 0.2f

typedef short short8 __attribute__((ext_vector_type(8)));
typedef float f32x16 __attribute__((ext_vector_type(16)));
typedef __attribute__((address_space(3))) unsigned int lds_u32;
typedef const __attribute__((address_space(1))) unsigned int glb_u32;

// ---------------- bf16 helpers ----------------
__device__ __forceinline__ unsigned bf16rne(float f) {
  union { float f; unsigned u; } v;
  v.f = f;
  return (v.u + 0x7FFFu + ((v.u >> 16) & 1u)) >> 16;
}
__device__ __forceinline__ float bf16tof(unsigned b) {
  union { unsigned u; float f; } v;
  v.u = b << 16;
  return v.f;
}
// truncation split of A: hi = trunc16(f); lo = trunc16(f - hi). err ~2^-16.
__device__ __forceinline__ void tsplit8(float4 a, float4 b, short8& hi,
                                        short8& lo) {
  float fa[8] = {a.x, a.y, a.z, a.w, b.x, b.y, b.z, b.w};
#pragma unroll
  for (int i = 0; i < 8; i++) {
    unsigned u = __float_as_uint(fa[i]);
    hi[i] = (short)(u >> 16);
    float lof = fa[i] - __uint_as_float(u & 0xffff0000u);
    lo[i] = (short)(__float_as_uint(lof) >> 16);
  }
}

// ---------------- W pre-pack (hi plane only) into MFMA B-frag order --------
__global__ void pack_w(const float* __restrict__ W, short* __restrict__ Bhi,
                       int N) {
  int k = blockIdx.x, n = threadIdx.x;
  float w = W[(size_t)k * N + n];
  int ksub = k >> 4, kh = (k >> 3) & 1, j = k & 7;
  int nsub = n >> 5, lane2 = (n & 31) | (kh << 5);
  size_t off = (((size_t)ksub * (N >> 5) + nsub) * 64 + lane2) * 8 + j;
  Bhi[off] = (short)bf16rne(w);
}

// ---------------- split-bf16 MFMA GEMM v5 ----------------
// LDS-staged A via async global_load_lds (width 16), double-buffered, with
// XOR bank swizzle applied on the global source address (linear LDS dest,
// rule #21: source perm == read perm). Block = 4 waves. NTILES=4: all waves
// share one 32-row mtile, each owns 64 cols. NTILES=1: each wave owns its own
// 32-row mtile (128 rows/block). B stays register-prefetched from global
// (L2-resident). MFMA order/numerics identical to v4.
template <int K, int NSUBS, int NTILES>
__global__ __launch_bounds__(256) void gemm_mfma(
    const float* __restrict__ A, const short* __restrict__ Bhi_,
    unsigned short* __restrict__ Cb, const float* __restrict__ alv,
    const float* __restrict__ arv, float* __restrict__ el,
    float* __restrict__ er, int M) {
  constexpr int N = NSUBS * 32;
  constexpr int MT = 4 / NTILES;   // 8-row segments staged per wave
  constexpr int BROWS = MT * 32;   // rows per block
  constexpr int T = K / 32;        // K-steps of 32 floats
  __shared__ float ldsb[2][BROWS * 32];  // [buf][row*32 + pos*4 + e]

  const int tid = threadIdx.x;
  const int lane = tid & 63;
  const int w = tid >> 6;
  const int l31 = lane & 31;
  const int half = lane >> 5;
  const int local_mt = w / NTILES;
  const int ntile = w % NTILES;
  const int block_row0 = blockIdx.x * BROWS;

  // --- staging source pointers (per-lane, carry the inverse swizzle) ---
  // HW writes lane i's 16B at ldsbase + i*16 (wave-uniform dest, m104).
  // Lane i covers (row r = seg*8 + (i>>3), pos = i&7); pos holds logical
  // K-chunk c = pos ^ (r&7).
  const float* gsrc[MT];
#pragma unroll
  for (int q = 0; q < MT; q++) {
    int seg = w * MT + q;
    int r = seg * 8 + (lane >> 3);
    int c = (lane & 7) ^ (r & 7);
    int grow = block_row0 + r;
    if (grow > M - 1) grow = M - 1;  // clamp tail rows (dup rows harmless)
    gsrc[q] = A + (size_t)grow * K + c * 4;
  }
  // wave-uniform LDS segment bases (floats)
  unsigned lbase[MT];
#pragma unroll
  for (int q = 0; q < MT; q++) lbase[q] = (w * MT + q) * 256;

  const short8* bh = (const short8*)Bhi_;
  const size_t bbase = (size_t)(ntile * 2) * 64 + lane;

  // row this lane reads back from LDS, and its swizzle key
  const int arow = local_mt * 32 + l31;
  const int rs = arow & 7;

  f32x16 acc0 = {}, acc1 = {};
  short8 cb0[2], cb1[2];

  // --- prologue: stage K-step 0, preload B for step 0 ---
#pragma unroll
  for (int q = 0; q < MT; q++) {
    __builtin_amdgcn_global_load_lds((glb_u32*)(gsrc[q]),
                                     (lds_u32*)&ldsb[0][lbase[q]], 16, 0, 0);
  }
#pragma unroll
  for (int u = 0; u < 2; u++) {
    size_t bb = bbase + (size_t)u * NSUBS * 64;
    cb0[u] = bh[bb];
    cb1[u] = bh[bb + 64];
  }
  __syncthreads();

  int buf = 0;
  for (int t = 0; t < T; t++) {
    // stage next K-step into the other buffer (async, flies across MFMAs)
    if (t + 1 < T) {
      int kb = (t + 1) * 32;
#pragma unroll
      for (int q = 0; q < MT; q++) {
        __builtin_amdgcn_global_load_lds((glb_u32*)(gsrc[q] + kb),
                                         (lds_u32*)&ldsb[buf ^ 1][lbase[q]],
                                         16, 0, 0);
      }
    }
    // prefetch next step's B fragments into registers
    int tn = (t + 1 < T) ? t + 1 : t;
    short8 nb0[2], nb1[2];
#pragma unroll
    for (int u = 0; u < 2; u++) {
      size_t bb = bbase + (size_t)(tn * 2 + u) * NSUBS * 64;
      nb0[u] = bh[bb];
      nb1[u] = bh[bb + 64];
    }
    // compute current step from LDS
    const float* lb = ldsb[buf];
#pragma unroll
    for (int u = 0; u < 2; u++) {
      int c0 = u * 4 + half * 2;
      float4 a0 = *(const float4*)&lb[arow * 32 + (c0 ^ rs) * 4];
      float4 a1 = *(const float4*)&lb[arow * 32 + ((c0 + 1) ^ rs) * 4];
      short8 ah, al8;
      tsplit8(a0, a1, ah, al8);
      acc0 = __builtin_amdgcn_mfma_f32_32x32x16_bf16(ah, cb0[u], acc0, 0, 0, 0);
      acc0 = __builtin_amdgcn_mfma_f32_32x32x16_bf16(al8, cb0[u], acc0, 0, 0, 0);
      acc1 = __builtin_amdgcn_mfma_f32_32x32x16_bf16(ah, cb1[u], acc1, 0, 0, 0);
      acc1 = __builtin_amdgcn_mfma_f32_32x32x16_bf16(al8, cb1[u], acc1, 0, 0, 0);
    }
    __syncthreads();  // drains vmcnt+lgkmcnt: next buffer staged, cur consumed
#pragma unroll
    for (int u = 0; u < 2; u++) {
      cb0[u] = nb0[u];
      cb1[u] = nb1[u];
    }
    buf ^= 1;
  }

  // C/D layout (m74/m101): col=lane&31, row=(r&3)+8*(r>>2)+4*half
  int colbase = ntile * 64 + l31;
  float wa0 = alv[colbase], wa1 = alv[colbase + 32];
  float wr0 = arv[colbase], wr1 = arv[colbase + 32];
  const int mrow0 = block_row0 + local_mt * 32;
#pragma unroll
  for (int r = 0; r < 16; r++) {
    int roff = (r & 3) + 8 * (r >> 2) + 4 * half;
    int row = mrow0 + roff;
    if (row < M) {
      Cb[(size_t)row * N + colbase] = (unsigned short)bf16rne(acc0[r]);
      Cb[(size_t)row * N + colbase + 32] = (unsigned short)bf16rne(acc1[r]);
    }
    float elv = acc0[r] * wa0 + acc1[r] * wa1;
    float erv = acc0[r] * wr0 + acc1[r] * wr1;
#pragma unroll
    for (int off = 1; off < 32; off <<= 1) {
      elv += __shfl_xor(elv, off);
      erv += __shfl_xor(erv, off);
    }
    if (l31 == 0 && row < M) {
      el[row * NTILES + ntile] = elv;
      er[row * NTILES + ntile] = erv;
    }
  }
}

// ---------------- CSR build ----------------
__global__ void hist_kernel(const int* __restrict__ dst,
                            int* __restrict__ counts) {
  int e = blockIdx.x * blockDim.x + threadIdx.x;
  if (e < N_EDGES) atomicAdd(&counts[dst[e]], 1);
}

#define NSCAN 196  // ceil(50000/256)
__global__ __launch_bounds__(256) void scan_part(const int* __restrict__ counts,
                                                 int* __restrict__ offsets,
                                                 int* __restrict__ bsums) {
  __shared__ int sh[256];
  int t = threadIdx.x;
  int i = blockIdx.x * 256 + t;
  int v = (i < N_NODES) ? counts[i] : 0;
  sh[t] = v;
  __syncthreads();
  for (int o = 1; o < 256; o <<= 1) {
    int x = (t >= o) ? sh[t - o] : 0;
    __syncthreads();
    sh[t] += x;
    __syncthreads();
  }
  if (i < N_NODES) offsets[i] = sh[t] - v;
  if (t == 255) bsums[blockIdx.x] = sh[255];
}
__global__ __launch_bounds__(256) void scan_top(int* __restrict__ bsums) {
  __shared__ int sh[256];
  int t = threadIdx.x;
  int v = (t < NSCAN) ? bsums[t] : 0;
  sh[t] = v;
  __syncthreads();
  for (int o = 1; o < 256; o <<= 1) {
    int x = (t >= o) ? sh[t - o] : 0;
    __syncthreads();
    sh[t] += x;
    __syncthreads();
  }
  if (t < NSCAN) bsums[t] = sh[t] - v;
}
__global__ __launch_bounds__(256) void scan_add(int* __restrict__ offsets,
                                                const int* __restrict__ bsums) {
  int i = blockIdx.x * 256 + threadIdx.x;
  if (i < N_NODES) offsets[i] += bsums[blockIdx.x];
  if (i == 0) offsets[N_NODES] = N_EDGES;
}

__global__ void scatter_kernel(const int* __restrict__ src,
                               const int* __restrict__ dst,
                               const int* __restrict__ offsets,
                               int* __restrict__ fill,
                               int* __restrict__ csr_src) {
  int e = blockIdx.x * blockDim.x + threadIdx.x;
  if (e < N_EDGES) {
    int d = dst[e];
    int pos = offsets[d] + atomicAdd(&fill[d], 1);
    csr_src[pos] = src[e];
  }
}

// ---------------- softmax max/denominator (online), separate ----------------
__global__ __launch_bounds__(256) void mden1_kernel(
    const int* __restrict__ offsets, const int* __restrict__ csr_src,
    const float* __restrict__ el, const float* __restrict__ er,
    float* __restrict__ mout, float* __restrict__ dout) {
  int w = threadIdx.x >> 6, lane = threadIdx.x & 63;
  int n = blockIdx.x * 4 + w;
  if (n >= N_NODES) return;
  int off0 = offsets[n], deg = offsets[n + 1] - off0;
  float4 erv = ((const float4*)er)[n];
  float er4[4] = {erv.x, erv.y, erv.z, erv.w};
  float m[4] = {-1e30f, -1e30f, -1e30f, -1e30f};
  float l[4] = {0.f, 0.f, 0.f, 0.f};
  for (int i = lane; i < deg; i += 64) {
    int s = csr_src[off0 + i];
    float4 elv = ((const float4*)el)[s];
    float e4[4] = {elv.x, elv.y, elv.z, elv.w};
#pragma unroll
    for (int h = 0; h < 4; h++) {
      float v = e4[h] + er4[h];
      v = v > 0.f ? v : NEG_SLOPE * v;
      float nm = fmaxf(m[h], v);
      l[h] = l[h] * __expf(m[h] - nm) + __expf(v - nm);
      m[h] = nm;
    }
  }
  for (int d = 32; d; d >>= 1) {
#pragma unroll
    for (int h = 0; h < 4; h++) {
      float mo = __shfl_down(m[h], d);
      float lo = __shfl_down(l[h], d);
      float nm = fmaxf(m[h], mo);
      l[h] = l[h] * __expf(m[h] - nm) + lo * __expf(mo - nm);
      m[h] = nm;
    }
  }
  if (lane == 0) {
#pragma unroll
    for (int h = 0; h < 4; h++) {
      mout[n * 4 + h] = m[h];
      dout[n * 4 + h] = l[h];
    }
  }
}

__global__ __launch_bounds__(256) void mden2_kernel(
    const int* __restrict__ offsets, const int* __restrict__ csr_src,
    const float* __restrict__ el, const float* __restrict__ er,
    float* __restrict__ mout, float* __restrict__ dout) {
  int w = threadIdx.x >> 6, lane = threadIdx.x & 63;
  int n = blockIdx.x * 4 + w;
  if (n >= N_NODES) return;
  int off0 = offsets[n], deg = offsets[n + 1] - off0;
  float ern = er[n];
  float m = -1e30f, l = 0.f;
  for (int i = lane; i < deg; i += 64) {
    int s = csr_src[off0 + i];
    float v = el[s] + ern;
    v = v > 0.f ? v : NEG_SLOPE * v;
    float nm = fmaxf(m, v);
    l = l * __expf(m - nm) + __expf(v - nm);
    m = nm;
  }
  for (int d = 32; d; d >>= 1) {
    float mo = __shfl_down(m, d);
    float lo = __shfl_down(l, d);
    float nm = fmaxf(m, mo);
    l = l * __expf(m - nm) + lo * __expf(mo - nm);
    m = nm;
  }
  if (lane == 0) {
    mout[n] = m;
    dout[n] = l;
  }
}

// ---------------- aggregation layer 1: bf16 gather, 2x unroll ----------------
__global__ __launch_bounds__(256) void agg1_kernel(
    const int* __restrict__ offsets, const int* __restrict__ csr_src,
    const float* __restrict__ el, const float* __restrict__ er,
    const float* __restrict__ mm, const float* __restrict__ den,
    const unsigned short* __restrict__ fb, const float* __restrict__ bias,
    float* __restrict__ h1) {
  __shared__ float red[3][256];
  int n = blockIdx.x;
  int t = threadIdx.x;
  int w = t >> 6, lane = t & 63;
  int h = lane >> 4;
  int off0 = offsets[n], deg = offsets[n + 1] - off0;
  float erh = er[n * 4 + h];
  float mh = mm[n * 4 + h];
  float invd = 1.0f / den[n * 4 + h];
  float4 acc = {0.f, 0.f, 0.f, 0.f};
  float4 acc2 = {0.f, 0.f, 0.f, 0.f};
  int i = w;
  for (; i + 4 < deg; i += 8) {
    int s0 = csr_src[off0 + i];
    int s1 = csr_src[off0 + i + 4];
    float e0 = el[s0 * 4 + h] + erh;
    float e1 = el[s1 * 4 + h] + erh;
    e0 = e0 > 0.f ? e0 : NEG_SLOPE * e0;
    e1 = e1 > 0.f ? e1 : NEG_SLOPE * e1;
    float a0 = __expf(e0 - mh) * invd;
    float a1 = __expf(e1 - mh) * invd;
    uint2 p0 = *(const uint2*)(fb + (size_t)s0 * 256 + lane * 4);
    uint2 p1 = *(const uint2*)(fb + (size_t)s1 * 256 + lane * 4);
    acc.x += a0 * __uint_as_float(p0.x << 16);
    acc.y += a0 * __uint_as_float(p0.x & 0xffff0000u);
    acc.z += a0 * __uint_as_float(p0.y << 16);
    acc.w += a0 * __uint_as_float(p0.y & 0xffff0000u);
    acc2.x += a1 * __uint_as_float(p1.x << 16);
    acc2.y += a1 * __uint_as_float(p1.x & 0xffff0000u);
    acc2.z += a1 * __uint_as_float(p1.y << 16);
    acc2.w += a1 * __uint_as_float(p1.y & 0xffff0000u);
  }
  if (i < deg) {
    int s0 = csr_src[off0 + i];
    float e0 = el[s0 * 4 + h] + erh;
    e0 = e0 > 0.f ? e0 : NEG_SLOPE * e0;
    float a0 = __expf(e0 - mh) * invd;
    uint2 p0 = *(const uint2*)(fb + (size_t)s0 * 256 + lane * 4);
    acc.x += a0 * __uint_as_float(p0.x << 16);
    acc.y += a0 * __uint_as_float(p0.x & 0xffff0000u);
    acc.z += a0 * __uint_as_float(p0.y << 16);
    acc.w += a0 * __uint_as_float(p0.y & 0xffff0000u);
  }
  acc.x += acc2.x;
  acc.y += acc2.y;
  acc.z += acc2.z;
  acc.w += acc2.w;
  if (w) *(float4*)(&red[w - 1][lane * 4]) = acc;
  __syncthreads();
  if (w == 0) {
    float4 r0 = *(float4*)(&red[0][lane * 4]);
    float4 r1 = *(float4*)(&red[1][lane * 4]);
    float4 r2 = *(float4*)(&red[2][lane * 4]);
    float4 b = ((const float4*)bias)[lane];
    float o[4] = {acc.x + r0.x + r1.x + r2.x + b.x,
                  acc.y + r0.y + r1.y + r2.y + b.y,
                  acc.z + r0.z + r1.z + r2.z + b.z,
                  acc.w + r0.w + r1.w + r2.w + b.w};
#pragma unroll
    for (int j = 0; j < 4; j++) o[j] = o[j] > 0.f ? o[j] : __expf(o[j]) - 1.0f;
    float4 ov = {o[0], o[1], o[2], o[3]};
    *(float4*)(h1 + (size_t)n * 256 + lane * 4) = ov;
  }
}

// ---------------- aggregation layer 2: bf16 gather ----------------
__global__ __launch_bounds__(256) void agg2_kernel(
    const int* __restrict__ offsets, const int* __restrict__ csr_src,
    const float* __restrict__ el, const float* __restrict__ er,
    const float* __restrict__ mm, const float* __restrict__ den,
    const unsigned short* __restrict__ fb2, const float* __restrict__ bias,
    float* __restrict__ out) {
  int w = threadIdx.x >> 6, lane = threadIdx.x & 63;
  int n = blockIdx.x * 4 + w;
  if (n >= N_NODES) return;
  int dg = lane & 15, eslot = lane >> 4;
  int off0 = offsets[n], deg = offsets[n + 1] - off0;
  float ern = er[n], mn = mm[n];
  float invd = 1.0f / den[n];
  float4 acc = {0.f, 0.f, 0.f, 0.f};
  for (int i = eslot; i < deg; i += 4) {
    int s = csr_src[off0 + i];
    float e = el[s] + ern;
    e = e > 0.f ? e : NEG_SLOPE * e;
    float a = __expf(e - mn) * invd;
    uint2 p = *(const uint2*)(fb2 + (size_t)s * 64 + dg * 4);
    acc.x += a * __uint_as_float(p.x << 16);
    acc.y += a * __uint_as_float(p.x & 0xffff0000u);
    acc.z += a * __uint_as_float(p.y << 16);
    acc.w += a * __uint_as_float(p.y & 0xffff0000u);
  }
#pragma unroll
  for (int off = 16; off < 64; off <<= 1) {
    acc.x += __shfl_xor(acc.x, off);
    acc.y += __shfl_xor(acc.y, off);
    acc.z += __shfl_xor(acc.z, off);
    acc.w += __shfl_xor(acc.w, off);
  }
  if (eslot == 0) {
    float4 b = ((const float4*)bias)[dg];
    float4 ov = {acc.x + b.x, acc.y + b.y, acc.z + b.z, acc.w + b.w};
    *(float4*)(out + (size_t)n * 64 + dg * 4) = ov;
  }
}

extern "C" void kernel_launch(void* const* d_in, const int* in_sizes, int n_in,
                              void* d_out, int out_size, void* d_ws,
                              size_t ws_size, hipStream_t stream) {
  const float* features = (const float*)d_in[0];
  const float* W1 = (const float*)d_in[1];
  const float* al1 = (const float*)d_in[2];
  const float* ar1 = (const float*)d_in[3];
  const float* b1 = (const float*)d_in[4];
  const float* W2 = (const float*)d_in[5];
  const float* al2 = (const float*)d_in[6];
  const float* ar2 = (const float*)d_in[7];
  const float* b2 = (const float*)d_in[8];
  const int* src = (const int*)d_in[9];
  const int* dst = (const int*)d_in[10];
  float* out = (float*)d_out;

  // Workspace (~84 MB):
  //  h1 fp32 [N,256] (agg1 out -> gemm2 A)
  //  fb bf16 [N,256] (gemm1 out) -> dead after agg1 -> fb2 bf16 [N,64] reuses
  float* h1 = (float*)d_ws;                                            // 51.2
  unsigned short* fb = (unsigned short*)(h1 + (size_t)N_NODES * 256);  // 25.6
  unsigned short* fb2 = fb;  // reuse (6.4 MB needed)
  float* el1 = (float*)(fb + (size_t)N_NODES * 256);
  float* er1 = el1 + N_NODES * 4;
  float* m1 = er1 + N_NODES * 4;
  float* d1 = m1 + N_NODES * 4;
  float* el2 = d1 + N_NODES * 4;
  float* er2 = el2 + N_NODES;
  float* m2 = er2 + N_NODES;
  float* d2 = m2 + N_NODES;
  int* counts = (int*)(d2 + N_NODES);
  int* offsets = counts + N_NODES;
  int* fill = offsets + N_NODES + 1;
  int* csr_src = fill + N_NODES;
  int* bsums = csr_src + N_EDGES;

  // W packs (hi plane only): b1 in d_out (dead until agg2);
  // b2 in `fill` (dead after scatter).
  short* b1hi = (short*)d_out;   // 512*256 shorts = 262 KB << 12.8 MB
  short* b2hi = (short*)fill;    // 256*64 shorts = 32 KB << 200 KB

  // --- CSR build ---
  hipMemsetAsync(counts, 0, N_NODES * sizeof(int), stream);
  hipMemsetAsync(fill, 0, N_NODES * sizeof(int), stream);
  hist_kernel<<<(N_EDGES + 255) / 256, 256, 0, stream>>>(dst, counts);
  scan_part<<<NSCAN, 256, 0, stream>>>(counts, offsets, bsums);
  scan_top<<<1, 256, 0, stream>>>(bsums);
  scan_add<<<NSCAN, 256, 0, stream>>>(offsets, bsums);
  scatter_kernel<<<(N_EDGES + 255) / 256, 256, 0, stream>>>(src, dst, offsets,
                                                            fill, csr_src);

  // --- weight packing ---
  pack_w<<<512, 256, 0, stream>>>(W1, b1hi, 256);
  pack_w<<<256, 64, 0, stream>>>(W2, b2hi, 64);

  // --- layer 1 (el/er fused into gemm epilogue) ---
  gemm_mfma<IN_DIM, 8, 4><<<1563, 256, 0, stream>>>(features, b1hi, fb, al1,
                                                    ar1, el1, er1, N_NODES);
  mden1_kernel<<<(N_NODES + 3) / 4, 256, 0, stream>>>(offsets, csr_src, el1,
                                                      er1, m1, d1);
  agg1_kernel<<<N_NODES, 256, 0, stream>>>(offsets, csr_src, el1, er1, m1, d1,
                                           fb, b1, h1);

  // --- layer 2 (el/er fused into gemm epilogue) ---
  gemm_mfma<256, 2, 1><<<391, 256, 0, stream>>>(h1, b2hi, fb2, al2, ar2, el2,
                                                er2, N_NODES);
  mden2_kernel<<<(N_NODES + 3) / 4, 256, 0, stream>>>(offsets, csr_src, el2,
                                                      er2, m2, d2);
  agg2_kernel<<<(N_NODES + 3) / 4, 256, 0, stream>>>(offsets, csr_src, el2, er2,
                                                     m2, d2, fb2, b2, out);
}

// Round 3
// 408.161 us; speedup vs baseline: 1.2033x; 1.1427x over previous
//
#include <hip/hip_runtime.h>

#define N_NODES 50000
#define N_EDGES 800000
#define IN_DIM 512
#define NEG_SLOPE 0.2f

typedef short short8 __attribute__((ext_vector_type(8)));
typedef float f32x16 __attribute__((ext_vector_type(16)));
typedef __attribute__((address_space(3))) unsigned int lds_u32;
typedef const __attribute__((address_space(1))) unsigned int glb_u32;

// ---------------- bf16 helpers ----------------
__device__ __forceinline__ unsigned bf16rne(float f) {
  union { float f; unsigned u; } v;
  v.f = f;
  return (v.u + 0x7FFFu + ((v.u >> 16) & 1u)) >> 16;
}
// truncation split of A: hi = trunc16(f); lo = trunc16(f - hi). err ~2^-16.
__device__ __forceinline__ void tsplit8(float4 a, float4 b, short8& hi,
                                        short8& lo) {
  float fa[8] = {a.x, a.y, a.z, a.w, b.x, b.y, b.z, b.w};
#pragma unroll
  for (int i = 0; i < 8; i++) {
    unsigned u = __float_as_uint(fa[i]);
    hi[i] = (short)(u >> 16);
    float lof = fa[i] - __uint_as_float(u & 0xffff0000u);
    lo[i] = (short)(__float_as_uint(lof) >> 16);
  }
}

// ---------------- W pre-pack (hi plane only) into MFMA B-frag order --------
__global__ void pack_w(const float* __restrict__ W, short* __restrict__ Bhi,
                       int N) {
  int k = blockIdx.x, n = threadIdx.x;
  float w = W[(size_t)k * N + n];
  int ksub = k >> 4, kh = (k >> 3) & 1, j = k & 7;
  int nsub = n >> 5, lane2 = (n & 31) | (kh << 5);
  size_t off = (((size_t)ksub * (N >> 5) + nsub) * 64 + lane2) * 8 + j;
  Bhi[off] = (short)bf16rne(w);
}

// ---------------- split-bf16 MFMA GEMM v5 (unchanged, verified) ----------------
// LDS-staged A via async global_load_lds (width 16), double-buffered, with
// XOR bank swizzle applied on the global source address (linear LDS dest,
// rule #21: source perm == read perm).
template <int K, int NSUBS, int NTILES>
__global__ __launch_bounds__(256) void gemm_mfma(
    const float* __restrict__ A, const short* __restrict__ Bhi_,
    unsigned short* __restrict__ Cb, const float* __restrict__ alv,
    const float* __restrict__ arv, float* __restrict__ el,
    float* __restrict__ er, int M) {
  constexpr int N = NSUBS * 32;
  constexpr int MT = 4 / NTILES;   // 8-row segments staged per wave
  constexpr int BROWS = MT * 32;   // rows per block
  constexpr int T = K / 32;        // K-steps of 32 floats
  __shared__ float ldsb[2][BROWS * 32];  // [buf][row*32 + pos*4 + e]

  const int tid = threadIdx.x;
  const int lane = tid & 63;
  const int w = tid >> 6;
  const int l31 = lane & 31;
  const int half = lane >> 5;
  const int local_mt = w / NTILES;
  const int ntile = w % NTILES;
  const int block_row0 = blockIdx.x * BROWS;

  const float* gsrc[MT];
#pragma unroll
  for (int q = 0; q < MT; q++) {
    int seg = w * MT + q;
    int r = seg * 8 + (lane >> 3);
    int c = (lane & 7) ^ (r & 7);
    int grow = block_row0 + r;
    if (grow > M - 1) grow = M - 1;  // clamp tail rows (dup rows harmless)
    gsrc[q] = A + (size_t)grow * K + c * 4;
  }
  unsigned lbase[MT];
#pragma unroll
  for (int q = 0; q < MT; q++) lbase[q] = (w * MT + q) * 256;

  const short8* bh = (const short8*)Bhi_;
  const size_t bbase = (size_t)(ntile * 2) * 64 + lane;

  const int arow = local_mt * 32 + l31;
  const int rs = arow & 7;

  f32x16 acc0 = {}, acc1 = {};
  short8 cb0[2], cb1[2];

#pragma unroll
  for (int q = 0; q < MT; q++) {
    __builtin_amdgcn_global_load_lds((glb_u32*)(gsrc[q]),
                                     (lds_u32*)&ldsb[0][lbase[q]], 16, 0, 0);
  }
#pragma unroll
  for (int u = 0; u < 2; u++) {
    size_t bb = bbase + (size_t)u * NSUBS * 64;
    cb0[u] = bh[bb];
    cb1[u] = bh[bb + 64];
  }
  __syncthreads();

  int buf = 0;
  for (int t = 0; t < T; t++) {
    if (t + 1 < T) {
      int kb = (t + 1) * 32;
#pragma unroll
      for (int q = 0; q < MT; q++) {
        __builtin_amdgcn_global_load_lds((glb_u32*)(gsrc[q] + kb),
                                         (lds_u32*)&ldsb[buf ^ 1][lbase[q]],
                                         16, 0, 0);
      }
    }
    int tn = (t + 1 < T) ? t + 1 : t;
    short8 nb0[2], nb1[2];
#pragma unroll
    for (int u = 0; u < 2; u++) {
      size_t bb = bbase + (size_t)(tn * 2 + u) * NSUBS * 64;
      nb0[u] = bh[bb];
      nb1[u] = bh[bb + 64];
    }
    const float* lb = ldsb[buf];
#pragma unroll
    for (int u = 0; u < 2; u++) {
      int c0 = u * 4 + half * 2;
      float4 a0 = *(const float4*)&lb[arow * 32 + (c0 ^ rs) * 4];
      float4 a1 = *(const float4*)&lb[arow * 32 + ((c0 + 1) ^ rs) * 4];
      short8 ah, al8;
      tsplit8(a0, a1, ah, al8);
      acc0 = __builtin_amdgcn_mfma_f32_32x32x16_bf16(ah, cb0[u], acc0, 0, 0, 0);
      acc0 = __builtin_amdgcn_mfma_f32_32x32x16_bf16(al8, cb0[u], acc0, 0, 0, 0);
      acc1 = __builtin_amdgcn_mfma_f32_32x32x16_bf16(ah, cb1[u], acc1, 0, 0, 0);
      acc1 = __builtin_amdgcn_mfma_f32_32x32x16_bf16(al8, cb1[u], acc1, 0, 0, 0);
    }
    __syncthreads();
#pragma unroll
    for (int u = 0; u < 2; u++) {
      cb0[u] = nb0[u];
      cb1[u] = nb1[u];
    }
    buf ^= 1;
  }

  // C/D layout (m74/m101): col=lane&31, row=(r&3)+8*(r>>2)+4*half
  int colbase = ntile * 64 + l31;
  float wa0 = alv[colbase], wa1 = alv[colbase + 32];
  float wr0 = arv[colbase], wr1 = arv[colbase + 32];
  const int mrow0 = block_row0 + local_mt * 32;
#pragma unroll
  for (int r = 0; r < 16; r++) {
    int roff = (r & 3) + 8 * (r >> 2) + 4 * half;
    int row = mrow0 + roff;
    if (row < M) {
      Cb[(size_t)row * N + colbase] = (unsigned short)bf16rne(acc0[r]);
      Cb[(size_t)row * N + colbase + 32] = (unsigned short)bf16rne(acc1[r]);
    }
    float elv = acc0[r] * wa0 + acc1[r] * wa1;
    float erv = acc0[r] * wr0 + acc1[r] * wr1;
#pragma unroll
    for (int off = 1; off < 32; off <<= 1) {
      elv += __shfl_xor(elv, off);
      erv += __shfl_xor(erv, off);
    }
    if (l31 == 0 && row < M) {
      el[row * NTILES + ntile] = elv;
      er[row * NTILES + ntile] = erv;
    }
  }
}

// ---------------- CSR build ----------------
__global__ void hist_kernel(const int* __restrict__ dst,
                            int* __restrict__ counts) {
  int e = blockIdx.x * blockDim.x + threadIdx.x;
  if (e < N_EDGES) atomicAdd(&counts[dst[e]], 1);
}

#define NSCAN 196  // ceil(50000/256)
__global__ __launch_bounds__(256) void scan_part(const int* __restrict__ counts,
                                                 int* __restrict__ offsets,
                                                 int* __restrict__ bsums) {
  __shared__ int sh[256];
  int t = threadIdx.x;
  int i = blockIdx.x * 256 + t;
  int v = (i < N_NODES) ? counts[i] : 0;
  sh[t] = v;
  __syncthreads();
  for (int o = 1; o < 256; o <<= 1) {
    int x = (t >= o) ? sh[t - o] : 0;
    __syncthreads();
    sh[t] += x;
    __syncthreads();
  }
  if (i < N_NODES) offsets[i] = sh[t] - v;
  if (t == 255) bsums[blockIdx.x] = sh[255];
}
__global__ __launch_bounds__(256) void scan_top(int* __restrict__ bsums) {
  __shared__ int sh[256];
  int t = threadIdx.x;
  int v = (t < NSCAN) ? bsums[t] : 0;
  sh[t] = v;
  __syncthreads();
  for (int o = 1; o < 256; o <<= 1) {
    int x = (t >= o) ? sh[t - o] : 0;
    __syncthreads();
    sh[t] += x;
    __syncthreads();
  }
  if (t < NSCAN) bsums[t] = sh[t] - v;
}
__global__ __launch_bounds__(256) void scan_add(int* __restrict__ offsets,
                                                const int* __restrict__ bsums) {
  int i = blockIdx.x * 256 + threadIdx.x;
  if (i < N_NODES) offsets[i] += bsums[blockIdx.x];
  if (i == 0) offsets[N_NODES] = N_EDGES;
}

__global__ void scatter_kernel(const int* __restrict__ src,
                               const int* __restrict__ dst,
                               const int* __restrict__ offsets,
                               int* __restrict__ fill,
                               int* __restrict__ csr_src) {
  int e = blockIdx.x * blockDim.x + threadIdx.x;
  if (e < N_EDGES) {
    int d = dst[e];
    int pos = offsets[d] + atomicAdd(&fill[d], 1);
    csr_src[pos] = src[e];
  }
}

// ---------------- aggregation layer 1 v2 ----------------
// Fused softmax denominator (exp without max-subtraction; |e| <~ 3 so safe),
// uint4 gathers (16B/lane, 32 lanes/row -> 2 edges per wave in parallel),
// 2x edge unroll -> 4 gathers in flight per wave. mden pass eliminated.
__global__ __launch_bounds__(256) void agg1_kernel(
    const int* __restrict__ offsets, const int* __restrict__ csr_src,
    const float* __restrict__ el, const float* __restrict__ er,
    const unsigned short* __restrict__ fb, const float* __restrict__ bias,
    float* __restrict__ h1) {
  __shared__ float red[3][256];
  __shared__ float dred[3][32];
  int n = blockIdx.x;
  int t = threadIdx.x;
  int w = t >> 6, lane = t & 63;
  int l31 = lane & 31;
  int eslot = lane >> 5;      // 0/1: which edge of the pair this half-wave does
  int h = l31 >> 3;           // head for this lane's 8 dims
  int slot = w * 2 + eslot;   // 0..7 edge slots per node
  int off0 = offsets[n], deg = offsets[n + 1] - off0;
  float erh = er[n * 4 + h];
  float4 aLo = {0.f, 0.f, 0.f, 0.f}, aHi = {0.f, 0.f, 0.f, 0.f};
  float4 bLo = {0.f, 0.f, 0.f, 0.f}, bHi = {0.f, 0.f, 0.f, 0.f};
  float sden = 0.f;
  int i = slot;
  for (; i + 8 < deg; i += 16) {
    int s0 = csr_src[off0 + i];
    int s1 = csr_src[off0 + i + 8];
    uint4 p0 = *(const uint4*)(fb + (size_t)s0 * 256 + l31 * 8);
    uint4 p1 = *(const uint4*)(fb + (size_t)s1 * 256 + l31 * 8);
    float e0 = el[s0 * 4 + h] + erh;
    float e1 = el[s1 * 4 + h] + erh;
    e0 = e0 > 0.f ? e0 : NEG_SLOPE * e0;
    e1 = e1 > 0.f ? e1 : NEG_SLOPE * e1;
    float a0 = __expf(e0), a1 = __expf(e1);
    sden += a0 + a1;
    aLo.x += a0 * __uint_as_float(p0.x << 16);
    aLo.y += a0 * __uint_as_float(p0.x & 0xffff0000u);
    aLo.z += a0 * __uint_as_float(p0.y << 16);
    aLo.w += a0 * __uint_as_float(p0.y & 0xffff0000u);
    aHi.x += a0 * __uint_as_float(p0.z << 16);
    aHi.y += a0 * __uint_as_float(p0.z & 0xffff0000u);
    aHi.z += a0 * __uint_as_float(p0.w << 16);
    aHi.w += a0 * __uint_as_float(p0.w & 0xffff0000u);
    bLo.x += a1 * __uint_as_float(p1.x << 16);
    bLo.y += a1 * __uint_as_float(p1.x & 0xffff0000u);
    bLo.z += a1 * __uint_as_float(p1.y << 16);
    bLo.w += a1 * __uint_as_float(p1.y & 0xffff0000u);
    bHi.x += a1 * __uint_as_float(p1.z << 16);
    bHi.y += a1 * __uint_as_float(p1.z & 0xffff0000u);
    bHi.z += a1 * __uint_as_float(p1.w << 16);
    bHi.w += a1 * __uint_as_float(p1.w & 0xffff0000u);
  }
  if (i < deg) {
    int s0 = csr_src[off0 + i];
    uint4 p0 = *(const uint4*)(fb + (size_t)s0 * 256 + l31 * 8);
    float e0 = el[s0 * 4 + h] + erh;
    e0 = e0 > 0.f ? e0 : NEG_SLOPE * e0;
    float a0 = __expf(e0);
    sden += a0;
    aLo.x += a0 * __uint_as_float(p0.x << 16);
    aLo.y += a0 * __uint_as_float(p0.x & 0xffff0000u);
    aLo.z += a0 * __uint_as_float(p0.y << 16);
    aLo.w += a0 * __uint_as_float(p0.y & 0xffff0000u);
    aHi.x += a0 * __uint_as_float(p0.z << 16);
    aHi.y += a0 * __uint_as_float(p0.z & 0xffff0000u);
    aHi.z += a0 * __uint_as_float(p0.w << 16);
    aHi.w += a0 * __uint_as_float(p0.w & 0xffff0000u);
  }
  // combine the 2-edge unroll
  aLo.x += bLo.x; aLo.y += bLo.y; aLo.z += bLo.z; aLo.w += bLo.w;
  aHi.x += bHi.x; aHi.y += bHi.y; aHi.z += bHi.z; aHi.w += bHi.w;
  // combine eslots (lane ^ 32)
  aLo.x += __shfl_xor(aLo.x, 32);
  aLo.y += __shfl_xor(aLo.y, 32);
  aLo.z += __shfl_xor(aLo.z, 32);
  aLo.w += __shfl_xor(aLo.w, 32);
  aHi.x += __shfl_xor(aHi.x, 32);
  aHi.y += __shfl_xor(aHi.y, 32);
  aHi.z += __shfl_xor(aHi.z, 32);
  aHi.w += __shfl_xor(aHi.w, 32);
  sden += __shfl_xor(sden, 32);
  if (w && lane < 32) {
    *(float4*)(&red[w - 1][l31 * 8]) = aLo;
    *(float4*)(&red[w - 1][l31 * 8 + 4]) = aHi;
    dred[w - 1][l31] = sden;
  }
  __syncthreads();
  if (w == 0 && lane < 32) {
    float den = sden;
#pragma unroll
    for (int j = 0; j < 3; j++) {
      float4 rL = *(float4*)(&red[j][l31 * 8]);
      float4 rH = *(float4*)(&red[j][l31 * 8 + 4]);
      aLo.x += rL.x; aLo.y += rL.y; aLo.z += rL.z; aLo.w += rL.w;
      aHi.x += rH.x; aHi.y += rH.y; aHi.z += rH.z; aHi.w += rH.w;
      den += dred[j][l31];
    }
    float invd = den > 0.f ? 1.0f / den : 0.f;
    float4 b0 = ((const float4*)bias)[l31 * 2];
    float4 b1 = ((const float4*)bias)[l31 * 2 + 1];
    float o[8] = {aLo.x * invd + b0.x, aLo.y * invd + b0.y,
                  aLo.z * invd + b0.z, aLo.w * invd + b0.w,
                  aHi.x * invd + b1.x, aHi.y * invd + b1.y,
                  aHi.z * invd + b1.z, aHi.w * invd + b1.w};
#pragma unroll
    for (int j = 0; j < 8; j++) o[j] = o[j] > 0.f ? o[j] : __expf(o[j]) - 1.0f;
    float4 o0 = {o[0], o[1], o[2], o[3]};
    float4 o1 = {o[4], o[5], o[6], o[7]};
    *(float4*)(h1 + (size_t)n * 256 + l31 * 8) = o0;
    *(float4*)(h1 + (size_t)n * 256 + l31 * 8 + 4) = o1;
  }
}

// ---------------- aggregation layer 2 v2 (fused den, 2x unroll) -------------
__global__ __launch_bounds__(256) void agg2_kernel(
    const int* __restrict__ offsets, const int* __restrict__ csr_src,
    const float* __restrict__ el, const float* __restrict__ er,
    const unsigned short* __restrict__ fb2, const float* __restrict__ bias,
    float* __restrict__ out) {
  int w = threadIdx.x >> 6, lane = threadIdx.x & 63;
  int n = blockIdx.x * 4 + w;
  if (n >= N_NODES) return;
  int dg = lane & 15, eslot = lane >> 4;
  int off0 = offsets[n], deg = offsets[n + 1] - off0;
  float ern = er[n];
  float4 acc = {0.f, 0.f, 0.f, 0.f};
  float4 acc2 = {0.f, 0.f, 0.f, 0.f};
  float sden = 0.f;
  int i = eslot;
  for (; i + 4 < deg; i += 8) {
    int s0 = csr_src[off0 + i];
    int s1 = csr_src[off0 + i + 4];
    uint2 p0 = *(const uint2*)(fb2 + (size_t)s0 * 64 + dg * 4);
    uint2 p1 = *(const uint2*)(fb2 + (size_t)s1 * 64 + dg * 4);
    float e0 = el[s0] + ern;
    float e1 = el[s1] + ern;
    e0 = e0 > 0.f ? e0 : NEG_SLOPE * e0;
    e1 = e1 > 0.f ? e1 : NEG_SLOPE * e1;
    float a0 = __expf(e0), a1 = __expf(e1);
    sden += a0 + a1;
    acc.x += a0 * __uint_as_float(p0.x << 16);
    acc.y += a0 * __uint_as_float(p0.x & 0xffff0000u);
    acc.z += a0 * __uint_as_float(p0.y << 16);
    acc.w += a0 * __uint_as_float(p0.y & 0xffff0000u);
    acc2.x += a1 * __uint_as_float(p1.x << 16);
    acc2.y += a1 * __uint_as_float(p1.x & 0xffff0000u);
    acc2.z += a1 * __uint_as_float(p1.y << 16);
    acc2.w += a1 * __uint_as_float(p1.y & 0xffff0000u);
  }
  if (i < deg) {
    int s0 = csr_src[off0 + i];
    uint2 p0 = *(const uint2*)(fb2 + (size_t)s0 * 64 + dg * 4);
    float e0 = el[s0] + ern;
    e0 = e0 > 0.f ? e0 : NEG_SLOPE * e0;
    float a0 = __expf(e0);
    sden += a0;
    acc.x += a0 * __uint_as_float(p0.x << 16);
    acc.y += a0 * __uint_as_float(p0.x & 0xffff0000u);
    acc.z += a0 * __uint_as_float(p0.y << 16);
    acc.w += a0 * __uint_as_float(p0.y & 0xffff0000u);
  }
  acc.x += acc2.x;
  acc.y += acc2.y;
  acc.z += acc2.z;
  acc.w += acc2.w;
#pragma unroll
  for (int off = 16; off < 64; off <<= 1) {
    acc.x += __shfl_xor(acc.x, off);
    acc.y += __shfl_xor(acc.y, off);
    acc.z += __shfl_xor(acc.z, off);
    acc.w += __shfl_xor(acc.w, off);
    sden += __shfl_xor(sden, off);
  }
  if (eslot == 0) {
    float invd = sden > 0.f ? 1.0f / sden : 0.f;
    float4 b = ((const float4*)bias)[dg];
    float4 ov = {acc.x * invd + b.x, acc.y * invd + b.y, acc.z * invd + b.z,
                 acc.w * invd + b.w};
    *(float4*)(out + (size_t)n * 64 + dg * 4) = ov;
  }
}

extern "C" void kernel_launch(void* const* d_in, const int* in_sizes, int n_in,
                              void* d_out, int out_size, void* d_ws,
                              size_t ws_size, hipStream_t stream) {
  const float* features = (const float*)d_in[0];
  const float* W1 = (const float*)d_in[1];
  const float* al1 = (const float*)d_in[2];
  const float* ar1 = (const float*)d_in[3];
  const float* b1 = (const float*)d_in[4];
  const float* W2 = (const float*)d_in[5];
  const float* al2 = (const float*)d_in[6];
  const float* ar2 = (const float*)d_in[7];
  const float* b2 = (const float*)d_in[8];
  const int* src = (const int*)d_in[9];
  const int* dst = (const int*)d_in[10];
  float* out = (float*)d_out;

  // Workspace (~80 MB):
  //  h1 fp32 [N,256] (agg1 out -> gemm2 A)
  //  fb bf16 [N,256] (gemm1 out) -> dead after agg1 -> fb2 bf16 [N,64] reuses
  float* h1 = (float*)d_ws;                                            // 51.2
  unsigned short* fb = (unsigned short*)(h1 + (size_t)N_NODES * 256);  // 25.6
  unsigned short* fb2 = fb;  // reuse (6.4 MB needed)
  float* el1 = (float*)(fb + (size_t)N_NODES * 256);
  float* er1 = el1 + N_NODES * 4;
  float* el2 = er1 + N_NODES * 4;
  float* er2 = el2 + N_NODES;
  int* counts = (int*)(er2 + N_NODES);
  int* offsets = counts + N_NODES;
  int* fill = offsets + N_NODES + 1;
  int* csr_src = fill + N_NODES;
  int* bsums = csr_src + N_EDGES;

  // W packs (hi plane only): b1 in d_out (dead until agg2);
  // b2 in `fill` (dead after scatter).
  short* b1hi = (short*)d_out;   // 512*256 shorts = 262 KB << 12.8 MB
  short* b2hi = (short*)fill;    // 256*64 shorts = 32 KB << 200 KB

  // --- CSR build ---
  hipMemsetAsync(counts, 0, N_NODES * sizeof(int), stream);
  hipMemsetAsync(fill, 0, N_NODES * sizeof(int), stream);
  hist_kernel<<<(N_EDGES + 255) / 256, 256, 0, stream>>>(dst, counts);
  scan_part<<<NSCAN, 256, 0, stream>>>(counts, offsets, bsums);
  scan_top<<<1, 256, 0, stream>>>(bsums);
  scan_add<<<NSCAN, 256, 0, stream>>>(offsets, bsums);
  scatter_kernel<<<(N_EDGES + 255) / 256, 256, 0, stream>>>(src, dst, offsets,
                                                            fill, csr_src);

  // --- weight packing ---
  pack_w<<<512, 256, 0, stream>>>(W1, b1hi, 256);
  pack_w<<<256, 64, 0, stream>>>(W2, b2hi, 64);

  // --- layer 1 (el/er fused into gemm epilogue; den fused into agg) ---
  gemm_mfma<IN_DIM, 8, 4><<<1563, 256, 0, stream>>>(features, b1hi, fb, al1,
                                                    ar1, el1, er1, N_NODES);
  agg1_kernel<<<N_NODES, 256, 0, stream>>>(offsets, csr_src, el1, er1, fb, b1,
                                           h1);

  // --- layer 2 ---
  gemm_mfma<256, 2, 1><<<391, 256, 0, stream>>>(h1, b2hi, fb2, al2, ar2, el2,
                                                er2, N_NODES);
  agg2_kernel<<<(N_NODES + 3) / 4, 256, 0, stream>>>(offsets, csr_src, el2,
                                                     er2, fb2, b2, out);
}

// Round 4
// 407.791 us; speedup vs baseline: 1.2044x; 1.0009x over previous
//
#include <hip/hip_runtime.h>

#define N_NODES 50000
#define N_EDGES 800000
#define IN_DIM 512
#define NEG_SLOPE 0.2f

typedef short short8 __attribute__((ext_vector_type(8)));
typedef float f32x16 __attribute__((ext_vector_type(16)));
typedef __attribute__((address_space(3))) unsigned int lds_u32;
typedef const __attribute__((address_space(1))) unsigned int glb_u32;

// ---------------- bf16 helpers ----------------
__device__ __forceinline__ unsigned bf16rne(float f) {
  union { float f; unsigned u; } v;
  v.f = f;
  return (v.u + 0x7FFFu + ((v.u >> 16) & 1u)) >> 16;
}
// truncation split of A: hi = trunc16(f); lo = trunc16(f - hi). err ~2^-16.
__device__ __forceinline__ void tsplit8(float4 a, float4 b, short8& hi,
                                        short8& lo) {
  float fa[8] = {a.x, a.y, a.z, a.w, b.x, b.y, b.z, b.w};
#pragma unroll
  for (int i = 0; i < 8; i++) {
    unsigned u = __float_as_uint(fa[i]);
    hi[i] = (short)(u >> 16);
    float lof = fa[i] - __uint_as_float(u & 0xffff0000u);
    lo[i] = (short)(__float_as_uint(lof) >> 16);
  }
}

// ---------------- W pre-pack (hi plane only) into MFMA B-frag order --------
__global__ void pack_w(const float* __restrict__ W, short* __restrict__ Bhi,
                       int N) {
  int k = blockIdx.x, n = threadIdx.x;
  float w = W[(size_t)k * N + n];
  int ksub = k >> 4, kh = (k >> 3) & 1, j = k & 7;
  int nsub = n >> 5, lane2 = (n & 31) | (kh << 5);
  size_t off = (((size_t)ksub * (N >> 5) + nsub) * 64 + lane2) * 8 + j;
  Bhi[off] = (short)bf16rne(w);
}

// ---------------- split-bf16 MFMA GEMM v6 ----------------
// K-step 64, double-buffered LDS A-staging (global_load_lds width 16, XOR
// swizzle on global source; rule #21), B prefetched 1 step ahead in regs
// (launch_bounds(256,2) so the prefetch survives regalloc). Per wave per
// step: RG*16 MFMAs between barriers (4x the v5 density).
// NTILES=4: waves split 256 cols, share 64 rows (RG=2). NTILES=1: waves
// stack rows (RG=1, 128 rows/block). Numerics identical to v5.
template <int K, int NSUBS, int NTILES, int RG>
__global__ __launch_bounds__(256, 2) void gemm_mfma(
    const float* __restrict__ A, const short* __restrict__ Bhi_,
    unsigned short* __restrict__ Cb, const float* __restrict__ alv,
    const float* __restrict__ arv, float* __restrict__ el,
    float* __restrict__ er, int M) {
  constexpr int N = NSUBS * 32;
  constexpr int MT = 4 / NTILES;        // wave row-stack depth
  constexpr int BROWS = MT * RG * 32;   // rows per block
  constexpr int T = K / 64;             // K-steps of 64 floats
  constexpr int GPW = BROWS / 16;       // gloads per wave per step
  __shared__ float ldsb[2][BROWS * 64];  // [buf][row*64 + pos*4 + e]

  const int tid = threadIdx.x;
  const int lane = tid & 63;
  const int w = tid >> 6;
  const int l31 = lane & 31;
  const int half = lane >> 5;
  const int local_mt = w / NTILES;
  const int ntile = w % NTILES;
  const int block_row0 = blockIdx.x * BROWS;

  // --- staging source pointers (per-lane, carry the inverse swizzle) ---
  // gload g writes lane i's 16B at chunk g*64+i: row r = g*4+(i>>4),
  // pos p = i&15. pos p holds logical chunk c = (p&8)|((p&7)^(r&7)).
  const float* gsrc[GPW];
#pragma unroll
  for (int q = 0; q < GPW; q++) {
    int g = w * GPW + q;
    int r = g * 4 + (lane >> 4);
    int p = lane & 15;
    int c = (p & 8) | ((p & 7) ^ (r & 7));
    int grow = block_row0 + r;
    if (grow > M - 1) grow = M - 1;  // clamp tail rows (dup rows harmless)
    gsrc[q] = A + (size_t)grow * K + c * 4;
  }

  const short8* bh = (const short8*)Bhi_;

  f32x16 acc[RG][2] = {};
  short8 cb[4][2], nb[4][2];

  // --- prologue: stage K-step 0, preload B for step 0 ---
#pragma unroll
  for (int q = 0; q < GPW; q++) {
    __builtin_amdgcn_global_load_lds(
        (glb_u32*)(gsrc[q]), (lds_u32*)&ldsb[0][(w * GPW + q) * 256], 16, 0,
        0);
  }
#pragma unroll
  for (int s = 0; s < 4; s++) {
#pragma unroll
    for (int g = 0; g < 2; g++) {
      cb[s][g] = bh[(size_t)(s * NSUBS + ntile * 2 + g) * 64 + lane];
    }
  }
  __syncthreads();

  int buf = 0;
  for (int t = 0; t < T; t++) {
    // stage next K-step (async, flies across MFMAs) + prefetch next B
    if (t + 1 < T) {
      int kb = (t + 1) * 64;
#pragma unroll
      for (int q = 0; q < GPW; q++) {
        __builtin_amdgcn_global_load_lds(
            (glb_u32*)(gsrc[q] + kb),
            (lds_u32*)&ldsb[buf ^ 1][(w * GPW + q) * 256], 16, 0, 0);
      }
#pragma unroll
      for (int s = 0; s < 4; s++) {
#pragma unroll
        for (int g = 0; g < 2; g++) {
          nb[s][g] =
              bh[(size_t)(((t + 1) * 4 + s) * NSUBS + ntile * 2 + g) * 64 +
                 lane];
        }
      }
    }
    // compute current step from LDS
    const float* lb = ldsb[buf];
#pragma unroll
    for (int rg = 0; rg < RG; rg++) {
      const int arow = local_mt * RG * 32 + rg * 32 + l31;
      const int rs = arow & 7;
#pragma unroll
      for (int s = 0; s < 4; s++) {
        int c0 = s * 4 + half * 2;
        int p0 = (c0 & 8) | ((c0 & 7) ^ rs);
        int p1 = ((c0 + 1) & 8) | (((c0 + 1) & 7) ^ rs);
        float4 a0 = *(const float4*)&lb[arow * 64 + p0 * 4];
        float4 a1 = *(const float4*)&lb[arow * 64 + p1 * 4];
        short8 ah, al8;
        tsplit8(a0, a1, ah, al8);
        acc[rg][0] =
            __builtin_amdgcn_mfma_f32_32x32x16_bf16(ah, cb[s][0], acc[rg][0], 0, 0, 0);
        acc[rg][0] =
            __builtin_amdgcn_mfma_f32_32x32x16_bf16(al8, cb[s][0], acc[rg][0], 0, 0, 0);
        acc[rg][1] =
            __builtin_amdgcn_mfma_f32_32x32x16_bf16(ah, cb[s][1], acc[rg][1], 0, 0, 0);
        acc[rg][1] =
            __builtin_amdgcn_mfma_f32_32x32x16_bf16(al8, cb[s][1], acc[rg][1], 0, 0, 0);
      }
    }
    __syncthreads();  // drains vmcnt+lgkmcnt: next buffer staged, cur consumed
    if (t + 1 < T) {
#pragma unroll
      for (int s = 0; s < 4; s++) {
#pragma unroll
        for (int g = 0; g < 2; g++) cb[s][g] = nb[s][g];
      }
    }
    buf ^= 1;
  }

  // C/D layout (m74/m101): col=lane&31, row=(r&3)+8*(r>>2)+4*half
  int colbase = ntile * 64 + l31;
  float wa0 = alv[colbase], wa1 = alv[colbase + 32];
  float wr0 = arv[colbase], wr1 = arv[colbase + 32];
#pragma unroll
  for (int rg = 0; rg < RG; rg++) {
    const int mrow0 = block_row0 + local_mt * RG * 32 + rg * 32;
#pragma unroll
    for (int r = 0; r < 16; r++) {
      int roff = (r & 3) + 8 * (r >> 2) + 4 * half;
      int row = mrow0 + roff;
      if (row < M) {
        Cb[(size_t)row * N + colbase] = (unsigned short)bf16rne(acc[rg][0][r]);
        Cb[(size_t)row * N + colbase + 32] =
            (unsigned short)bf16rne(acc[rg][1][r]);
      }
      float elv = acc[rg][0][r] * wa0 + acc[rg][1][r] * wa1;
      float erv = acc[rg][0][r] * wr0 + acc[rg][1][r] * wr1;
#pragma unroll
      for (int off = 1; off < 32; off <<= 1) {
        elv += __shfl_xor(elv, off);
        erv += __shfl_xor(erv, off);
      }
      if (l31 == 0 && row < M) {
        el[row * NTILES + ntile] = elv;
        er[row * NTILES + ntile] = erv;
      }
    }
  }
}

// ---------------- CSR build ----------------
__global__ void hist_kernel(const int* __restrict__ dst,
                            int* __restrict__ counts) {
  int e = blockIdx.x * blockDim.x + threadIdx.x;
  if (e < N_EDGES) atomicAdd(&counts[dst[e]], 1);
}

#define NSCAN 196  // ceil(50000/256)
__global__ __launch_bounds__(256) void scan_part(const int* __restrict__ counts,
                                                 int* __restrict__ offsets,
                                                 int* __restrict__ bsums) {
  __shared__ int sh[256];
  int t = threadIdx.x;
  int i = blockIdx.x * 256 + t;
  int v = (i < N_NODES) ? counts[i] : 0;
  sh[t] = v;
  __syncthreads();
  for (int o = 1; o < 256; o <<= 1) {
    int x = (t >= o) ? sh[t - o] : 0;
    __syncthreads();
    sh[t] += x;
    __syncthreads();
  }
  if (i < N_NODES) offsets[i] = sh[t] - v;
  if (t == 255) bsums[blockIdx.x] = sh[255];
}
__global__ __launch_bounds__(256) void scan_top(int* __restrict__ bsums) {
  __shared__ int sh[256];
  int t = threadIdx.x;
  int v = (t < NSCAN) ? bsums[t] : 0;
  sh[t] = v;
  __syncthreads();
  for (int o = 1; o < 256; o <<= 1) {
    int x = (t >= o) ? sh[t - o] : 0;
    __syncthreads();
    sh[t] += x;
    __syncthreads();
  }
  if (t < NSCAN) bsums[t] = sh[t] - v;
}
__global__ __launch_bounds__(256) void scan_add(int* __restrict__ offsets,
                                                const int* __restrict__ bsums) {
  int i = blockIdx.x * 256 + threadIdx.x;
  if (i < N_NODES) offsets[i] += bsums[blockIdx.x];
  if (i == 0) offsets[N_NODES] = N_EDGES;
}

__global__ void scatter_kernel(const int* __restrict__ src,
                               const int* __restrict__ dst,
                               const int* __restrict__ offsets,
                               int* __restrict__ fill,
                               int* __restrict__ csr_src) {
  int e = blockIdx.x * blockDim.x + threadIdx.x;
  if (e < N_EDGES) {
    int d = dst[e];
    int pos = offsets[d] + atomicAdd(&fill[d], 1);
    csr_src[pos] = src[e];
  }
}

// ---------------- aggregation layer 1 v2 ----------------
// Fused softmax denominator (exp without max-subtraction; |e| <~ 3 so safe),
// uint4 gathers (16B/lane, 32 lanes/row -> 2 edges per wave in parallel),
// 2x edge unroll -> 4 gathers in flight per wave. mden pass eliminated.
__global__ __launch_bounds__(256) void agg1_kernel(
    const int* __restrict__ offsets, const int* __restrict__ csr_src,
    const float* __restrict__ el, const float* __restrict__ er,
    const unsigned short* __restrict__ fb, const float* __restrict__ bias,
    float* __restrict__ h1) {
  __shared__ float red[3][256];
  __shared__ float dred[3][32];
  int n = blockIdx.x;
  int t = threadIdx.x;
  int w = t >> 6, lane = t & 63;
  int l31 = lane & 31;
  int eslot = lane >> 5;      // 0/1: which edge of the pair this half-wave does
  int h = l31 >> 3;           // head for this lane's 8 dims
  int slot = w * 2 + eslot;   // 0..7 edge slots per node
  int off0 = offsets[n], deg = offsets[n + 1] - off0;
  float erh = er[n * 4 + h];
  float4 aLo = {0.f, 0.f, 0.f, 0.f}, aHi = {0.f, 0.f, 0.f, 0.f};
  float4 bLo = {0.f, 0.f, 0.f, 0.f}, bHi = {0.f, 0.f, 0.f, 0.f};
  float sden = 0.f;
  int i = slot;
  for (; i + 8 < deg; i += 16) {
    int s0 = csr_src[off0 + i];
    int s1 = csr_src[off0 + i + 8];
    uint4 p0 = *(const uint4*)(fb + (size_t)s0 * 256 + l31 * 8);
    uint4 p1 = *(const uint4*)(fb + (size_t)s1 * 256 + l31 * 8);
    float e0 = el[s0 * 4 + h] + erh;
    float e1 = el[s1 * 4 + h] + erh;
    e0 = e0 > 0.f ? e0 : NEG_SLOPE * e0;
    e1 = e1 > 0.f ? e1 : NEG_SLOPE * e1;
    float a0 = __expf(e0), a1 = __expf(e1);
    sden += a0 + a1;
    aLo.x += a0 * __uint_as_float(p0.x << 16);
    aLo.y += a0 * __uint_as_float(p0.x & 0xffff0000u);
    aLo.z += a0 * __uint_as_float(p0.y << 16);
    aLo.w += a0 * __uint_as_float(p0.y & 0xffff0000u);
    aHi.x += a0 * __uint_as_float(p0.z << 16);
    aHi.y += a0 * __uint_as_float(p0.z & 0xffff0000u);
    aHi.z += a0 * __uint_as_float(p0.w << 16);
    aHi.w += a0 * __uint_as_float(p0.w & 0xffff0000u);
    bLo.x += a1 * __uint_as_float(p1.x << 16);
    bLo.y += a1 * __uint_as_float(p1.x & 0xffff0000u);
    bLo.z += a1 * __uint_as_float(p1.y << 16);
    bLo.w += a1 * __uint_as_float(p1.y & 0xffff0000u);
    bHi.x += a1 * __uint_as_float(p1.z << 16);
    bHi.y += a1 * __uint_as_float(p1.z & 0xffff0000u);
    bHi.z += a1 * __uint_as_float(p1.w << 16);
    bHi.w += a1 * __uint_as_float(p1.w & 0xffff0000u);
  }
  if (i < deg) {
    int s0 = csr_src[off0 + i];
    uint4 p0 = *(const uint4*)(fb + (size_t)s0 * 256 + l31 * 8);
    float e0 = el[s0 * 4 + h] + erh;
    e0 = e0 > 0.f ? e0 : NEG_SLOPE * e0;
    float a0 = __expf(e0);
    sden += a0;
    aLo.x += a0 * __uint_as_float(p0.x << 16);
    aLo.y += a0 * __uint_as_float(p0.x & 0xffff0000u);
    aLo.z += a0 * __uint_as_float(p0.y << 16);
    aLo.w += a0 * __uint_as_float(p0.y & 0xffff0000u);
    aHi.x += a0 * __uint_as_float(p0.z << 16);
    aHi.y += a0 * __uint_as_float(p0.z & 0xffff0000u);
    aHi.z += a0 * __uint_as_float(p0.w << 16);
    aHi.w += a0 * __uint_as_float(p0.w & 0xffff0000u);
  }
  // combine the 2-edge unroll
  aLo.x += bLo.x; aLo.y += bLo.y; aLo.z += bLo.z; aLo.w += bLo.w;
  aHi.x += bHi.x; aHi.y += bHi.y; aHi.z += bHi.z; aHi.w += bHi.w;
  // combine eslots (lane ^ 32)
  aLo.x += __shfl_xor(aLo.x, 32);
  aLo.y += __shfl_xor(aLo.y, 32);
  aLo.z += __shfl_xor(aLo.z, 32);
  aLo.w += __shfl_xor(aLo.w, 32);
  aHi.x += __shfl_xor(aHi.x, 32);
  aHi.y += __shfl_xor(aHi.y, 32);
  aHi.z += __shfl_xor(aHi.z, 32);
  aHi.w += __shfl_xor(aHi.w, 32);
  sden += __shfl_xor(sden, 32);
  if (w && lane < 32) {
    *(float4*)(&red[w - 1][l31 * 8]) = aLo;
    *(float4*)(&red[w - 1][l31 * 8 + 4]) = aHi;
    dred[w - 1][l31] = sden;
  }
  __syncthreads();
  if (w == 0 && lane < 32) {
    float den = sden;
#pragma unroll
    for (int j = 0; j < 3; j++) {
      float4 rL = *(float4*)(&red[j][l31 * 8]);
      float4 rH = *(float4*)(&red[j][l31 * 8 + 4]);
      aLo.x += rL.x; aLo.y += rL.y; aLo.z += rL.z; aLo.w += rL.w;
      aHi.x += rH.x; aHi.y += rH.y; aHi.z += rH.z; aHi.w += rH.w;
      den += dred[j][l31];
    }
    float invd = den > 0.f ? 1.0f / den : 0.f;
    float4 b0 = ((const float4*)bias)[l31 * 2];
    float4 b1 = ((const float4*)bias)[l31 * 2 + 1];
    float o[8] = {aLo.x * invd + b0.x, aLo.y * invd + b0.y,
                  aLo.z * invd + b0.z, aLo.w * invd + b0.w,
                  aHi.x * invd + b1.x, aHi.y * invd + b1.y,
                  aHi.z * invd + b1.z, aHi.w * invd + b1.w};
#pragma unroll
    for (int j = 0; j < 8; j++) o[j] = o[j] > 0.f ? o[j] : __expf(o[j]) - 1.0f;
    float4 o0 = {o[0], o[1], o[2], o[3]};
    float4 o1 = {o[4], o[5], o[6], o[7]};
    *(float4*)(h1 + (size_t)n * 256 + l31 * 8) = o0;
    *(float4*)(h1 + (size_t)n * 256 + l31 * 8 + 4) = o1;
  }
}

// ---------------- aggregation layer 2 v2 (fused den, 2x unroll) -------------
__global__ __launch_bounds__(256) void agg2_kernel(
    const int* __restrict__ offsets, const int* __restrict__ csr_src,
    const float* __restrict__ el, const float* __restrict__ er,
    const unsigned short* __restrict__ fb2, const float* __restrict__ bias,
    float* __restrict__ out) {
  int w = threadIdx.x >> 6, lane = threadIdx.x & 63;
  int n = blockIdx.x * 4 + w;
  if (n >= N_NODES) return;
  int dg = lane & 15, eslot = lane >> 4;
  int off0 = offsets[n], deg = offsets[n + 1] - off0;
  float ern = er[n];
  float4 acc = {0.f, 0.f, 0.f, 0.f};
  float4 acc2 = {0.f, 0.f, 0.f, 0.f};
  float sden = 0.f;
  int i = eslot;
  for (; i + 4 < deg; i += 8) {
    int s0 = csr_src[off0 + i];
    int s1 = csr_src[off0 + i + 4];
    uint2 p0 = *(const uint2*)(fb2 + (size_t)s0 * 64 + dg * 4);
    uint2 p1 = *(const uint2*)(fb2 + (size_t)s1 * 64 + dg * 4);
    float e0 = el[s0] + ern;
    float e1 = el[s1] + ern;
    e0 = e0 > 0.f ? e0 : NEG_SLOPE * e0;
    e1 = e1 > 0.f ? e1 : NEG_SLOPE * e1;
    float a0 = __expf(e0), a1 = __expf(e1);
    sden += a0 + a1;
    acc.x += a0 * __uint_as_float(p0.x << 16);
    acc.y += a0 * __uint_as_float(p0.x & 0xffff0000u);
    acc.z += a0 * __uint_as_float(p0.y << 16);
    acc.w += a0 * __uint_as_float(p0.y & 0xffff0000u);
    acc2.x += a1 * __uint_as_float(p1.x << 16);
    acc2.y += a1 * __uint_as_float(p1.x & 0xffff0000u);
    acc2.z += a1 * __uint_as_float(p1.y << 16);
    acc2.w += a1 * __uint_as_float(p1.y & 0xffff0000u);
  }
  if (i < deg) {
    int s0 = csr_src[off0 + i];
    uint2 p0 = *(const uint2*)(fb2 + (size_t)s0 * 64 + dg * 4);
    float e0 = el[s0] + ern;
    e0 = e0 > 0.f ? e0 : NEG_SLOPE * e0;
    float a0 = __expf(e0);
    sden += a0;
    acc.x += a0 * __uint_as_float(p0.x << 16);
    acc.y += a0 * __uint_as_float(p0.x & 0xffff0000u);
    acc.z += a0 * __uint_as_float(p0.y << 16);
    acc.w += a0 * __uint_as_float(p0.y & 0xffff0000u);
  }
  acc.x += acc2.x;
  acc.y += acc2.y;
  acc.z += acc2.z;
  acc.w += acc2.w;
#pragma unroll
  for (int off = 16; off < 64; off <<= 1) {
    acc.x += __shfl_xor(acc.x, off);
    acc.y += __shfl_xor(acc.y, off);
    acc.z += __shfl_xor(acc.z, off);
    acc.w += __shfl_xor(acc.w, off);
    sden += __shfl_xor(sden, off);
  }
  if (eslot == 0) {
    float invd = sden > 0.f ? 1.0f / sden : 0.f;
    float4 b = ((const float4*)bias)[dg];
    float4 ov = {acc.x * invd + b.x, acc.y * invd + b.y, acc.z * invd + b.z,
                 acc.w * invd + b.w};
    *(float4*)(out + (size_t)n * 64 + dg * 4) = ov;
  }
}

extern "C" void kernel_launch(void* const* d_in, const int* in_sizes, int n_in,
                              void* d_out, int out_size, void* d_ws,
                              size_t ws_size, hipStream_t stream) {
  const float* features = (const float*)d_in[0];
  const float* W1 = (const float*)d_in[1];
  const float* al1 = (const float*)d_in[2];
  const float* ar1 = (const float*)d_in[3];
  const float* b1 = (const float*)d_in[4];
  const float* W2 = (const float*)d_in[5];
  const float* al2 = (const float*)d_in[6];
  const float* ar2 = (const float*)d_in[7];
  const float* b2 = (const float*)d_in[8];
  const int* src = (const int*)d_in[9];
  const int* dst = (const int*)d_in[10];
  float* out = (float*)d_out;

  // Workspace (~80 MB):
  //  h1 fp32 [N,256] (agg1 out -> gemm2 A)
  //  fb bf16 [N,256] (gemm1 out) -> dead after agg1 -> fb2 bf16 [N,64] reuses
  float* h1 = (float*)d_ws;                                            // 51.2
  unsigned short* fb = (unsigned short*)(h1 + (size_t)N_NODES * 256);  // 25.6
  unsigned short* fb2 = fb;  // reuse (6.4 MB needed)
  float* el1 = (float*)(fb + (size_t)N_NODES * 256);
  float* er1 = el1 + N_NODES * 4;
  float* el2 = er1 + N_NODES * 4;
  float* er2 = el2 + N_NODES;
  int* counts = (int*)(er2 + N_NODES);
  int* offsets = counts + N_NODES;
  int* fill = offsets + N_NODES + 1;
  int* csr_src = fill + N_NODES;
  int* bsums = csr_src + N_EDGES;

  // W packs (hi plane only): b1 in d_out (dead until agg2);
  // b2 in `fill` (dead after scatter).
  short* b1hi = (short*)d_out;   // 512*256 shorts = 262 KB << 12.8 MB
  short* b2hi = (short*)fill;    // 256*64 shorts = 32 KB << 200 KB

  // --- CSR build ---
  hipMemsetAsync(counts, 0, N_NODES * sizeof(int), stream);
  hipMemsetAsync(fill, 0, N_NODES * sizeof(int), stream);
  hist_kernel<<<(N_EDGES + 255) / 256, 256, 0, stream>>>(dst, counts);
  scan_part<<<NSCAN, 256, 0, stream>>>(counts, offsets, bsums);
  scan_top<<<1, 256, 0, stream>>>(bsums);
  scan_add<<<NSCAN, 256, 0, stream>>>(offsets, bsums);
  scatter_kernel<<<(N_EDGES + 255) / 256, 256, 0, stream>>>(src, dst, offsets,
                                                            fill, csr_src);

  // --- weight packing ---
  pack_w<<<512, 256, 0, stream>>>(W1, b1hi, 256);
  pack_w<<<256, 64, 0, stream>>>(W2, b2hi, 64);

  // --- layer 1 (el/er fused into gemm epilogue; den fused into agg) ---
  gemm_mfma<IN_DIM, 8, 4, 2><<<782, 256, 0, stream>>>(features, b1hi, fb, al1,
                                                      ar1, el1, er1, N_NODES);
  agg1_kernel<<<N_NODES, 256, 0, stream>>>(offsets, csr_src, el1, er1, fb, b1,
                                           h1);

  // --- layer 2 ---
  gemm_mfma<256, 2, 1, 1><<<391, 256, 0, stream>>>(h1, b2hi, fb2, al2, ar2,
                                                   el2, er2, N_NODES);
  agg2_kernel<<<(N_NODES + 3) / 4, 256, 0, stream>>>(offsets, csr_src, el2,
                                                     er2, fb2, b2, out);
}

// Round 5
// 404.776 us; speedup vs baseline: 1.2134x; 1.0074x over previous
//
#include <hip/hip_runtime.h>

#define N_NODES 50000
#define N_EDGES 800000
#define IN_DIM 512
#define NEG_SLOPE 0.2f

typedef short short8 __attribute__((ext_vector_type(8)));
typedef float f32x16 __attribute__((ext_vector_type(16)));
typedef __attribute__((address_space(3))) unsigned int lds_u32;
typedef const __attribute__((address_space(1))) unsigned int glb_u32;

// ---------------- bf16 helpers ----------------
__device__ __forceinline__ unsigned bf16rne(float f) {
  union { float f; unsigned u; } v;
  v.f = f;
  return (v.u + 0x7FFFu + ((v.u >> 16) & 1u)) >> 16;
}
// truncation split of A: hi = trunc16(f); lo = trunc16(f - hi). err ~2^-16.
__device__ __forceinline__ void tsplit8(float4 a, float4 b, short8& hi,
                                        short8& lo) {
  float fa[8] = {a.x, a.y, a.z, a.w, b.x, b.y, b.z, b.w};
#pragma unroll
  for (int i = 0; i < 8; i++) {
    unsigned u = __float_as_uint(fa[i]);
    hi[i] = (short)(u >> 16);
    float lof = fa[i] - __uint_as_float(u & 0xffff0000u);
    lo[i] = (short)(__float_as_uint(lof) >> 16);
  }
}

// ---------------- W pre-pack (hi plane only) into MFMA B-frag order --------
__global__ void pack_w(const float* __restrict__ W, short* __restrict__ Bhi,
                       int N) {
  int k = blockIdx.x, n = threadIdx.x;
  float w = W[(size_t)k * N + n];
  int ksub = k >> 4, kh = (k >> 3) & 1, j = k & 7;
  int nsub = n >> 5, lane2 = (n & 31) | (kh << 5);
  size_t off = (((size_t)ksub * (N >> 5) + nsub) * 64 + lane2) * 8 + j;
  Bhi[off] = (short)bf16rne(w);
}

// ---------------- split-bf16 MFMA GEMM v7 ----------------
// v5 geometry (K-step 32, 32/128-row blocks) + T4 counted-vmcnt pipeline:
// A AND B staged via global_load_lds (5 loads/wave/step), double-buffered,
// raw s_barrier with s_waitcnt vmcnt(5) (never 0 in main loop) so next-step
// loads stay in flight across the barrier. End-of-iter lgkmcnt(0)+barrier
// guards WAR on the buffer being re-staged next iter. A-tile keeps the XOR
// bank swizzle on the global source (rule #21). Numerics identical to v5.
template <int K, int NSUBS, int NTILES>
__global__ __launch_bounds__(256) void gemm_mfma(
    const float* __restrict__ A, const short* __restrict__ Bhi_,
    unsigned short* __restrict__ Cb, const float* __restrict__ alv,
    const float* __restrict__ arv, float* __restrict__ el,
    float* __restrict__ er, int M) {
  constexpr int N = NSUBS * 32;
  constexpr int MT = 4 / NTILES;        // A gloads per wave per step
  constexpr int BROWS = MT * 32;        // rows per block
  constexpr int T = K / 32;             // K-steps of 32 floats
  constexpr int GB = NSUBS / 2;         // B gloads per wave per step
  constexpr int BSTEP_S = NSUBS * 1024; // shorts per B K-step (2 ksubs)
  static_assert(MT + GB == 5, "vmcnt literals assume 5 loads/wave/step");
  __shared__ float ldsA[2][BROWS * 32];  // [buf][row*32 + pos*4 + e]
  __shared__ short ldsB[2][BSTEP_S];     // [buf][frag-linear]

  const int tid = threadIdx.x;
  const int lane = tid & 63;
  const int w = tid >> 6;
  const int l31 = lane & 31;
  const int half = lane >> 5;
  const int local_mt = w / NTILES;
  const int ntile = w % NTILES;
  const int block_row0 = blockIdx.x * BROWS;

  // --- A staging source pointers (per-lane, carry the inverse swizzle) ---
  // gload (w,q) covers seg = w*MT+q (8 rows x 128B). Lane i -> row
  // r = seg*8 + (i>>3), pos p = i&7; pos p holds logical chunk c = p^(r&7).
  const float* gsrcA[MT];
#pragma unroll
  for (int q = 0; q < MT; q++) {
    int seg = w * MT + q;
    int r = seg * 8 + (lane >> 3);
    int c = (lane & 7) ^ (r & 7);
    int grow = block_row0 + r;
    if (grow > M - 1) grow = M - 1;  // clamp tail rows (dup rows harmless)
    gsrcA[q] = A + (size_t)grow * K + c * 4;
  }
  // B staging source (linear copy of the packed-B K-step region)
  const short* bsrc = Bhi_ + lane * 8;

  // row this lane reads back from LDS-A, and its swizzle key
  const int arow = local_mt * 32 + l31;
  const int rs = arow & 7;

  f32x16 acc0 = {}, acc1 = {};

  auto STAGE = [&](int b, int t) {
#pragma unroll
    for (int q = 0; q < MT; q++) {
      __builtin_amdgcn_global_load_lds((glb_u32*)(gsrcA[q] + t * 32),
                                       (lds_u32*)&ldsA[b][(w * MT + q) * 256],
                                       16, 0, 0);
    }
#pragma unroll
    for (int j = 0; j < GB; j++) {
      __builtin_amdgcn_global_load_lds(
          (glb_u32*)(bsrc + (size_t)t * BSTEP_S + (w * GB + j) * 512),
          (lds_u32*)&ldsB[b][(w * GB + j) * 512], 16, 0, 0);
    }
  };

  // --- prologue: stage K-step 0 ---
  STAGE(0, 0);

  int buf = 0;
  for (int t = 0; t < T; t++) {
    if (t + 1 < T) {
      STAGE(buf ^ 1, t + 1);  // issue next step; stays in flight across barrier
      asm volatile("s_waitcnt vmcnt(5)" ::: "memory");  // step-t loads done
    } else {
      asm volatile("s_waitcnt vmcnt(0)" ::: "memory");
    }
    __builtin_amdgcn_s_barrier();  // all waves' step-t stages landed

    const float* lA = ldsA[buf];
    const short* lB = ldsB[buf];
#pragma unroll
    for (int u = 0; u < 2; u++) {
      short8 cb0 = *(const short8*)&lB[(u * NSUBS + ntile * 2) * 512 + lane * 8];
      short8 cb1 =
          *(const short8*)&lB[(u * NSUBS + ntile * 2 + 1) * 512 + lane * 8];
      int c0 = u * 4 + half * 2;
      float4 a0 = *(const float4*)&lA[arow * 32 + (c0 ^ rs) * 4];
      float4 a1 = *(const float4*)&lA[arow * 32 + ((c0 + 1) ^ rs) * 4];
      short8 ah, al8;
      tsplit8(a0, a1, ah, al8);
      acc0 = __builtin_amdgcn_mfma_f32_32x32x16_bf16(ah, cb0, acc0, 0, 0, 0);
      acc0 = __builtin_amdgcn_mfma_f32_32x32x16_bf16(al8, cb0, acc0, 0, 0, 0);
      acc1 = __builtin_amdgcn_mfma_f32_32x32x16_bf16(ah, cb1, acc1, 0, 0, 0);
      acc1 = __builtin_amdgcn_mfma_f32_32x32x16_bf16(al8, cb1, acc1, 0, 0, 0);
    }
    // WAR guard: my LDS reads retired, then all waves synced, before next
    // iter re-stages this buffer.
    asm volatile("s_waitcnt lgkmcnt(0)" ::: "memory");
    __builtin_amdgcn_s_barrier();
    buf ^= 1;
  }

  // C/D layout (m74/m101): col=lane&31, row=(r&3)+8*(r>>2)+4*half
  int colbase = ntile * 64 + l31;
  float wa0 = alv[colbase], wa1 = alv[colbase + 32];
  float wr0 = arv[colbase], wr1 = arv[colbase + 32];
  const int mrow0 = block_row0 + local_mt * 32;
#pragma unroll
  for (int r = 0; r < 16; r++) {
    int roff = (r & 3) + 8 * (r >> 2) + 4 * half;
    int row = mrow0 + roff;
    if (row < M) {
      Cb[(size_t)row * N + colbase] = (unsigned short)bf16rne(acc0[r]);
      Cb[(size_t)row * N + colbase + 32] = (unsigned short)bf16rne(acc1[r]);
    }
    float elv = acc0[r] * wa0 + acc1[r] * wa1;
    float erv = acc0[r] * wr0 + acc1[r] * wr1;
#pragma unroll
    for (int off = 1; off < 32; off <<= 1) {
      elv += __shfl_xor(elv, off);
      erv += __shfl_xor(erv, off);
    }
    if (l31 == 0 && row < M) {
      el[row * NTILES + ntile] = elv;
      er[row * NTILES + ntile] = erv;
    }
  }
}

// ---------------- CSR build ----------------
__global__ void hist_kernel(const int* __restrict__ dst,
                            int* __restrict__ counts) {
  int e = blockIdx.x * blockDim.x + threadIdx.x;
  if (e < N_EDGES) atomicAdd(&counts[dst[e]], 1);
}

#define NSCAN 196  // ceil(50000/256)
__global__ __launch_bounds__(256) void scan_part(const int* __restrict__ counts,
                                                 int* __restrict__ offsets,
                                                 int* __restrict__ bsums) {
  __shared__ int sh[256];
  int t = threadIdx.x;
  int i = blockIdx.x * 256 + t;
  int v = (i < N_NODES) ? counts[i] : 0;
  sh[t] = v;
  __syncthreads();
  for (int o = 1; o < 256; o <<= 1) {
    int x = (t >= o) ? sh[t - o] : 0;
    __syncthreads();
    sh[t] += x;
    __syncthreads();
  }
  if (i < N_NODES) offsets[i] = sh[t] - v;
  if (t == 255) bsums[blockIdx.x] = sh[255];
}
__global__ __launch_bounds__(256) void scan_top(int* __restrict__ bsums) {
  __shared__ int sh[256];
  int t = threadIdx.x;
  int v = (t < NSCAN) ? bsums[t] : 0;
  sh[t] = v;
  __syncthreads();
  for (int o = 1; o < 256; o <<= 1) {
    int x = (t >= o) ? sh[t - o] : 0;
    __syncthreads();
    sh[t] += x;
    __syncthreads();
  }
  if (t < NSCAN) bsums[t] = sh[t] - v;
}
__global__ __launch_bounds__(256) void scan_add(int* __restrict__ offsets,
                                                const int* __restrict__ bsums) {
  int i = blockIdx.x * 256 + threadIdx.x;
  if (i < N_NODES) offsets[i] += bsums[blockIdx.x];
  if (i == 0) offsets[N_NODES] = N_EDGES;
}

__global__ void scatter_kernel(const int* __restrict__ src,
                               const int* __restrict__ dst,
                               const int* __restrict__ offsets,
                               int* __restrict__ fill,
                               int* __restrict__ csr_src) {
  int e = blockIdx.x * blockDim.x + threadIdx.x;
  if (e < N_EDGES) {
    int d = dst[e];
    int pos = offsets[d] + atomicAdd(&fill[d], 1);
    csr_src[pos] = src[e];
  }
}

// ---------------- aggregation layer 1 v2 ----------------
// Fused softmax denominator (exp without max-subtraction; |e| <~ 3 so safe),
// uint4 gathers (16B/lane, 32 lanes/row -> 2 edges per wave in parallel),
// 2x edge unroll -> 4 gathers in flight per wave. mden pass eliminated.
__global__ __launch_bounds__(256) void agg1_kernel(
    const int* __restrict__ offsets, const int* __restrict__ csr_src,
    const float* __restrict__ el, const float* __restrict__ er,
    const unsigned short* __restrict__ fb, const float* __restrict__ bias,
    float* __restrict__ h1) {
  __shared__ float red[3][256];
  __shared__ float dred[3][32];
  int n = blockIdx.x;
  int t = threadIdx.x;
  int w = t >> 6, lane = t & 63;
  int l31 = lane & 31;
  int eslot = lane >> 5;      // 0/1: which edge of the pair this half-wave does
  int h = l31 >> 3;           // head for this lane's 8 dims
  int slot = w * 2 + eslot;   // 0..7 edge slots per node
  int off0 = offsets[n], deg = offsets[n + 1] - off0;
  float erh = er[n * 4 + h];
  float4 aLo = {0.f, 0.f, 0.f, 0.f}, aHi = {0.f, 0.f, 0.f, 0.f};
  float4 bLo = {0.f, 0.f, 0.f, 0.f}, bHi = {0.f, 0.f, 0.f, 0.f};
  float sden = 0.f;
  int i = slot;
  for (; i + 8 < deg; i += 16) {
    int s0 = csr_src[off0 + i];
    int s1 = csr_src[off0 + i + 8];
    uint4 p0 = *(const uint4*)(fb + (size_t)s0 * 256 + l31 * 8);
    uint4 p1 = *(const uint4*)(fb + (size_t)s1 * 256 + l31 * 8);
    float e0 = el[s0 * 4 + h] + erh;
    float e1 = el[s1 * 4 + h] + erh;
    e0 = e0 > 0.f ? e0 : NEG_SLOPE * e0;
    e1 = e1 > 0.f ? e1 : NEG_SLOPE * e1;
    float a0 = __expf(e0), a1 = __expf(e1);
    sden += a0 + a1;
    aLo.x += a0 * __uint_as_float(p0.x << 16);
    aLo.y += a0 * __uint_as_float(p0.x & 0xffff0000u);
    aLo.z += a0 * __uint_as_float(p0.y << 16);
    aLo.w += a0 * __uint_as_float(p0.y & 0xffff0000u);
    aHi.x += a0 * __uint_as_float(p0.z << 16);
    aHi.y += a0 * __uint_as_float(p0.z & 0xffff0000u);
    aHi.z += a0 * __uint_as_float(p0.w << 16);
    aHi.w += a0 * __uint_as_float(p0.w & 0xffff0000u);
    bLo.x += a1 * __uint_as_float(p1.x << 16);
    bLo.y += a1 * __uint_as_float(p1.x & 0xffff0000u);
    bLo.z += a1 * __uint_as_float(p1.y << 16);
    bLo.w += a1 * __uint_as_float(p1.y & 0xffff0000u);
    bHi.x += a1 * __uint_as_float(p1.z << 16);
    bHi.y += a1 * __uint_as_float(p1.z & 0xffff0000u);
    bHi.z += a1 * __uint_as_float(p1.w << 16);
    bHi.w += a1 * __uint_as_float(p1.w & 0xffff0000u);
  }
  if (i < deg) {
    int s0 = csr_src[off0 + i];
    uint4 p0 = *(const uint4*)(fb + (size_t)s0 * 256 + l31 * 8);
    float e0 = el[s0 * 4 + h] + erh;
    e0 = e0 > 0.f ? e0 : NEG_SLOPE * e0;
    float a0 = __expf(e0);
    sden += a0;
    aLo.x += a0 * __uint_as_float(p0.x << 16);
    aLo.y += a0 * __uint_as_float(p0.x & 0xffff0000u);
    aLo.z += a0 * __uint_as_float(p0.y << 16);
    aLo.w += a0 * __uint_as_float(p0.y & 0xffff0000u);
    aHi.x += a0 * __uint_as_float(p0.z << 16);
    aHi.y += a0 * __uint_as_float(p0.z & 0xffff0000u);
    aHi.z += a0 * __uint_as_float(p0.w << 16);
    aHi.w += a0 * __uint_as_float(p0.w & 0xffff0000u);
  }
  // combine the 2-edge unroll
  aLo.x += bLo.x; aLo.y += bLo.y; aLo.z += bLo.z; aLo.w += bLo.w;
  aHi.x += bHi.x; aHi.y += bHi.y; aHi.z += bHi.z; aHi.w += bHi.w;
  // combine eslots (lane ^ 32)
  aLo.x += __shfl_xor(aLo.x, 32);
  aLo.y += __shfl_xor(aLo.y, 32);
  aLo.z += __shfl_xor(aLo.z, 32);
  aLo.w += __shfl_xor(aLo.w, 32);
  aHi.x += __shfl_xor(aHi.x, 32);
  aHi.y += __shfl_xor(aHi.y, 32);
  aHi.z += __shfl_xor(aHi.z, 32);
  aHi.w += __shfl_xor(aHi.w, 32);
  sden += __shfl_xor(sden, 32);
  if (w && lane < 32) {
    *(float4*)(&red[w - 1][l31 * 8]) = aLo;
    *(float4*)(&red[w - 1][l31 * 8 + 4]) = aHi;
    dred[w - 1][l31] = sden;
  }
  __syncthreads();
  if (w == 0 && lane < 32) {
    float den = sden;
#pragma unroll
    for (int j = 0; j < 3; j++) {
      float4 rL = *(float4*)(&red[j][l31 * 8]);
      float4 rH = *(float4*)(&red[j][l31 * 8 + 4]);
      aLo.x += rL.x; aLo.y += rL.y; aLo.z += rL.z; aLo.w += rL.w;
      aHi.x += rH.x; aHi.y += rH.y; aHi.z += rH.z; aHi.w += rH.w;
      den += dred[j][l31];
    }
    float invd = den > 0.f ? 1.0f / den : 0.f;
    float4 b0 = ((const float4*)bias)[l31 * 2];
    float4 b1 = ((const float4*)bias)[l31 * 2 + 1];
    float o[8] = {aLo.x * invd + b0.x, aLo.y * invd + b0.y,
                  aLo.z * invd + b0.z, aLo.w * invd + b0.w,
                  aHi.x * invd + b1.x, aHi.y * invd + b1.y,
                  aHi.z * invd + b1.z, aHi.w * invd + b1.w};
#pragma unroll
    for (int j = 0; j < 8; j++) o[j] = o[j] > 0.f ? o[j] : __expf(o[j]) - 1.0f;
    float4 o0 = {o[0], o[1], o[2], o[3]};
    float4 o1 = {o[4], o[5], o[6], o[7]};
    *(float4*)(h1 + (size_t)n * 256 + l31 * 8) = o0;
    *(float4*)(h1 + (size_t)n * 256 + l31 * 8 + 4) = o1;
  }
}

// ---------------- aggregation layer 2 v2 (fused den, 2x unroll) -------------
__global__ __launch_bounds__(256) void agg2_kernel(
    const int* __restrict__ offsets, const int* __restrict__ csr_src,
    const float* __restrict__ el, const float* __restrict__ er,
    const unsigned short* __restrict__ fb2, const float* __restrict__ bias,
    float* __restrict__ out) {
  int w = threadIdx.x >> 6, lane = threadIdx.x & 63;
  int n = blockIdx.x * 4 + w;
  if (n >= N_NODES) return;
  int dg = lane & 15, eslot = lane >> 4;
  int off0 = offsets[n], deg = offsets[n + 1] - off0;
  float ern = er[n];
  float4 acc = {0.f, 0.f, 0.f, 0.f};
  float4 acc2 = {0.f, 0.f, 0.f, 0.f};
  float sden = 0.f;
  int i = eslot;
  for (; i + 4 < deg; i += 8) {
    int s0 = csr_src[off0 + i];
    int s1 = csr_src[off0 + i + 4];
    uint2 p0 = *(const uint2*)(fb2 + (size_t)s0 * 64 + dg * 4);
    uint2 p1 = *(const uint2*)(fb2 + (size_t)s1 * 64 + dg * 4);
    float e0 = el[s0] + ern;
    float e1 = el[s1] + ern;
    e0 = e0 > 0.f ? e0 : NEG_SLOPE * e0;
    e1 = e1 > 0.f ? e1 : NEG_SLOPE * e1;
    float a0 = __expf(e0), a1 = __expf(e1);
    sden += a0 + a1;
    acc.x += a0 * __uint_as_float(p0.x << 16);
    acc.y += a0 * __uint_as_float(p0.x & 0xffff0000u);
    acc.z += a0 * __uint_as_float(p0.y << 16);
    acc.w += a0 * __uint_as_float(p0.y & 0xffff0000u);
    acc2.x += a1 * __uint_as_float(p1.x << 16);
    acc2.y += a1 * __uint_as_float(p1.x & 0xffff0000u);
    acc2.z += a1 * __uint_as_float(p1.y << 16);
    acc2.w += a1 * __uint_as_float(p1.y & 0xffff0000u);
  }
  if (i < deg) {
    int s0 = csr_src[off0 + i];
    uint2 p0 = *(const uint2*)(fb2 + (size_t)s0 * 64 + dg * 4);
    float e0 = el[s0] + ern;
    e0 = e0 > 0.f ? e0 : NEG_SLOPE * e0;
    float a0 = __expf(e0);
    sden += a0;
    acc.x += a0 * __uint_as_float(p0.x << 16);
    acc.y += a0 * __uint_as_float(p0.x & 0xffff0000u);
    acc.z += a0 * __uint_as_float(p0.y << 16);
    acc.w += a0 * __uint_as_float(p0.y & 0xffff0000u);
  }
  acc.x += acc2.x;
  acc.y += acc2.y;
  acc.z += acc2.z;
  acc.w += acc2.w;
#pragma unroll
  for (int off = 16; off < 64; off <<= 1) {
    acc.x += __shfl_xor(acc.x, off);
    acc.y += __shfl_xor(acc.y, off);
    acc.z += __shfl_xor(acc.z, off);
    acc.w += __shfl_xor(acc.w, off);
    sden += __shfl_xor(sden, off);
  }
  if (eslot == 0) {
    float invd = sden > 0.f ? 1.0f / sden : 0.f;
    float4 b = ((const float4*)bias)[dg];
    float4 ov = {acc.x * invd + b.x, acc.y * invd + b.y, acc.z * invd + b.z,
                 acc.w * invd + b.w};
    *(float4*)(out + (size_t)n * 64 + dg * 4) = ov;
  }
}

extern "C" void kernel_launch(void* const* d_in, const int* in_sizes, int n_in,
                              void* d_out, int out_size, void* d_ws,
                              size_t ws_size, hipStream_t stream) {
  const float* features = (const float*)d_in[0];
  const float* W1 = (const float*)d_in[1];
  const float* al1 = (const float*)d_in[2];
  const float* ar1 = (const float*)d_in[3];
  const float* b1 = (const float*)d_in[4];
  const float* W2 = (const float*)d_in[5];
  const float* al2 = (const float*)d_in[6];
  const float* ar2 = (const float*)d_in[7];
  const float* b2 = (const float*)d_in[8];
  const int* src = (const int*)d_in[9];
  const int* dst = (const int*)d_in[10];
  float* out = (float*)d_out;

  // Workspace (~80 MB):
  //  h1 fp32 [N,256] (agg1 out -> gemm2 A)
  //  fb bf16 [N,256] (gemm1 out) -> dead after agg1 -> fb2 bf16 [N,64] reuses
  float* h1 = (float*)d_ws;                                            // 51.2
  unsigned short* fb = (unsigned short*)(h1 + (size_t)N_NODES * 256);  // 25.6
  unsigned short* fb2 = fb;  // reuse (6.4 MB needed)
  float* el1 = (float*)(fb + (size_t)N_NODES * 256);
  float* er1 = el1 + N_NODES * 4;
  float* el2 = er1 + N_NODES * 4;
  float* er2 = el2 + N_NODES;
  int* counts = (int*)(er2 + N_NODES);
  int* offsets = counts + N_NODES;
  int* fill = offsets + N_NODES + 1;
  int* csr_src = fill + N_NODES;
  int* bsums = csr_src + N_EDGES;

  // W packs (hi plane only): b1 in d_out (dead until agg2);
  // b2 in `fill` (dead after scatter).
  short* b1hi = (short*)d_out;   // 512*256 shorts = 262 KB << 12.8 MB
  short* b2hi = (short*)fill;    // 256*64 shorts = 32 KB << 200 KB

  // --- CSR build ---
  hipMemsetAsync(counts, 0, N_NODES * sizeof(int), stream);
  hipMemsetAsync(fill, 0, N_NODES * sizeof(int), stream);
  hist_kernel<<<(N_EDGES + 255) / 256, 256, 0, stream>>>(dst, counts);
  scan_part<<<NSCAN, 256, 0, stream>>>(counts, offsets, bsums);
  scan_top<<<1, 256, 0, stream>>>(bsums);
  scan_add<<<NSCAN, 256, 0, stream>>>(offsets, bsums);
  scatter_kernel<<<(N_EDGES + 255) / 256, 256, 0, stream>>>(src, dst, offsets,
                                                            fill, csr_src);

  // --- weight packing ---
  pack_w<<<512, 256, 0, stream>>>(W1, b1hi, 256);
  pack_w<<<256, 64, 0, stream>>>(W2, b2hi, 64);

  // --- layer 1 (el/er fused into gemm epilogue; den fused into agg) ---
  gemm_mfma<IN_DIM, 8, 4><<<1563, 256, 0, stream>>>(features, b1hi, fb, al1,
                                                    ar1, el1, er1, N_NODES);
  agg1_kernel<<<N_NODES, 256, 0, stream>>>(offsets, csr_src, el1, er1, fb, b1,
                                           h1);

  // --- layer 2 ---
  gemm_mfma<256, 2, 1><<<391, 256, 0, stream>>>(h1, b2hi, fb2, al2, ar2, el2,
                                                er2, N_NODES);
  agg2_kernel<<<(N_NODES + 3) / 4, 256, 0, stream>>>(offsets, csr_src, el2,
                                                     er2, fb2, b2, out);
}